// Round 10
// baseline (84.950 us; speedup 1.0000x reference)
//
#include <hip/hip_runtime.h>
#include <math.h>

// ---------------------------------------------------------------------------
// 4-qubit statevector layer, fully collapsed:
//   e_w = sum_{t in {I,X,Z}^4} C_w[t] * prod_k m_k[t_k],  m_k = [1, sin x, cos x]
// Two kernels: build_C (1 block, d_ws) + qlayer_main (2 samples/thread).
// R10: sample-pair arithmetic packed into v2f (ext_vector_type(2)) so the
// backend emits v_pk_fma_f32 -> FMA instruction stream halves (~720 -> ~360
// per thread); qlayer becomes HBM-bound (~5.5us for 32MB).
// ---------------------------------------------------------------------------

typedef float v2f __attribute__((ext_vector_type(2)));

static __device__ __forceinline__ v2f vfma(v2f a, float s, v2f c) {
    return __builtin_elementwise_fma(a, (v2f){s, s}, c);   // v_pk_fma_f32
}

__global__ __launch_bounds__(256) void build_C(const float* __restrict__ qw,
                                               float* __restrict__ Cg) {
    __shared__ float g[16][8];          // per-gate 2x2 complex entries
    __shared__ float Ar[2][16][16];     // ping-pong Re state [buf][amp][col]
    __shared__ float Ai[2][16][16];
    __shared__ float ReE[4][16][16];    // Re(U^dag Z_w U)
    int t = threadIdx.x;
    int b = t >> 4, col = t & 15;

    if (t < 16) {
        float phi = qw[t * 3 + 0], theta = qw[t * 3 + 1], omega = qw[t * 3 + 2];
        float st, ct, sha, cha, shd, chd;
        __sincosf(0.5f * theta, &st, &ct);
        __sincosf(0.5f * (phi + omega), &sha, &cha);   // em = cha - i*sha
        __sincosf(0.5f * (phi - omega), &shd, &chd);   // ed = chd + i*shd
        g[t][0] =  cha * ct; g[t][1] = -sha * ct;   // u00
        g[t][2] = -chd * st; g[t][3] = -shd * st;   // u01
        g[t][4] =  chd * st; g[t][5] = -shd * st;   // u10
        g[t][6] =  cha * ct; g[t][7] =  sha * ct;   // u11
    }
    Ar[0][b][col] = (b == col) ? 1.f : 0.f;
    Ai[0][b][col] = 0.f;
    __syncthreads();

    // CNOT-ring permutation: new[b] = old[perm(b)]
    int perm = b;
#pragma unroll
    for (int w = 3; w >= 0; --w) {
        int cm = 8 >> w, tm = 8 >> ((w + 1) & 3);
        perm = (perm & cm) ? (perm ^ tm) : perm;
    }

    int p = 0;
    for (int l = 0; l < 4; ++l) {
#pragma unroll
        for (int w = 0; w < 4; ++w) {
            int gi = l * 4 + w;
            int m = 8 >> w;              // wire w <-> bit (3-w)
            int lo = b & ~m, hi = b | m;
            bool isHi = (b & m) != 0;
            float cAr = isHi ? g[gi][4] : g[gi][0];
            float cAi = isHi ? g[gi][5] : g[gi][1];
            float cBr = isHi ? g[gi][6] : g[gi][2];
            float cBi = isHi ? g[gi][7] : g[gi][3];
            float alor = Ar[p][lo][col], aloi = Ai[p][lo][col];
            float ahir = Ar[p][hi][col], ahii = Ai[p][hi][col];
            float nr = cAr * alor - cAi * aloi + cBr * ahir - cBi * ahii;
            float ni = cAr * aloi + cAi * alor + cBr * ahii + cBi * ahir;
            Ar[1 - p][b][col] = nr;
            Ai[1 - p][b][col] = ni;
            p = 1 - p;
            __syncthreads();
        }
        float nr = Ar[p][perm][col], ni = Ai[p][perm][col];
        Ar[1 - p][b][col] = nr;
        Ai[1 - p][b][col] = ni;
        p = 1 - p;
        __syncthreads();
    }

    // ReE_w[i][j] = sum_b z_w(b) * (Ur[b][i]Ur[b][j] + Ui[b][i]Ui[b][j])
    for (int idx = t; idx < 1024; idx += 256) {
        int w = idx >> 8, i = (idx >> 4) & 15, j = idx & 15;
        float acc = 0.f;
#pragma unroll
        for (int bb = 0; bb < 16; ++bb) {
            float z = ((bb >> (3 - w)) & 1) ? -1.f : 1.f;
            acc += z * (Ar[p][bb][i] * Ar[p][bb][j] + Ai[p][bb][i] * Ai[p][bb][j]);
        }
        ReE[w][i][j] = acc;
    }
    __syncthreads();

    // C[(t01*9+t23)*4 + w] = (1/16) sum_i sign_t(i) ReE_w[i][i^xmask]
    for (int idx = t; idx < 324; idx += 256) {
        int w = idx & 3, tt = idx >> 2;
        int t01 = tt / 9, t23 = tt % 9;
        int d0 = t01 / 3, d1 = t01 % 3, d2 = t23 / 3, d3 = t23 % 3;  // 0=I,1=X,2=Z
        int xmask = ((d0 == 1) << 3) | ((d1 == 1) << 2) | ((d2 == 1) << 1) | (d3 == 1);
        int zmask = ((d0 == 2) << 3) | ((d1 == 2) << 2) | ((d2 == 2) << 1) | (d3 == 2);
        float acc = 0.f;
#pragma unroll
        for (int i = 0; i < 16; ++i) {
            float sgn = (__popc(i & zmask) & 1) ? -1.f : 1.f;
            acc += sgn * ReE[w][i][i ^ xmask];
        }
        Cg[idx] = acc * 0.0625f;
    }
}

__global__ __launch_bounds__(256) void qlayer_main(
        const float4* __restrict__ x, const float* __restrict__ Cg,
        float4* __restrict__ out, int B) {
    __shared__ __align__(16) float C[324];
    for (int k = threadIdx.x; k < 324; k += 256) C[k] = Cg[k];
    __syncthreads();

    int half = B >> 1;
    int i = blockIdx.x * 256 + threadIdx.x;
    if (i >= half) {
        // odd-B tail (not hit for B=1M, kept for safety)
        if (i == half && (B & 1)) {
            float4 xv = x[B - 1];
            float s0, c0, s1, c1, s2, c2, s3, c3;
            __sincosf(xv.x, &s0, &c0); __sincosf(xv.y, &s1, &c1);
            __sincosf(xv.z, &s2, &c2); __sincosf(xv.w, &s3, &c3);
            float m0[3] = {1.f, s0, c0}, m1[3] = {1.f, s1, c1};
            float m2[3] = {1.f, s2, c2}, m3[3] = {1.f, s3, c3};
            float e0 = 0.f, e1 = 0.f, e2 = 0.f, e3 = 0.f;
            for (int t01 = 0; t01 < 9; ++t01)
                for (int t23 = 0; t23 < 9; ++t23) {
                    float mv = m0[t01 / 3] * m1[t01 % 3] * m2[t23 / 3] * m3[t23 % 3];
                    const float4 c4 = *(const float4*)&C[(t01 * 9 + t23) * 4];
                    e0 = fmaf(c4.x, mv, e0); e1 = fmaf(c4.y, mv, e1);
                    e2 = fmaf(c4.z, mv, e2); e3 = fmaf(c4.w, mv, e3);
                }
            out[B - 1] = make_float4(e0, e1, e2, e3);
        }
        return;
    }

    float4 xa = x[i];
    float4 xb = x[i + half];
    float as0, ac0, as1, ac1, as2, ac2, as3, ac3;
    float bs0, bc0, bs1, bc1, bs2, bc2, bs3, bc3;
    __sincosf(xa.x, &as0, &ac0); __sincosf(xa.y, &as1, &ac1);
    __sincosf(xa.z, &as2, &ac2); __sincosf(xa.w, &as3, &ac3);
    __sincosf(xb.x, &bs0, &bc0); __sincosf(xb.y, &bs1, &bc1);
    __sincosf(xb.z, &bs2, &bc2); __sincosf(xb.w, &bs3, &bc3);

    // packed per-qubit vectors: .x = sample a, .y = sample b
    v2f m0p[3] = {{1.f, 1.f}, {as0, bs0}, {ac0, bc0}};
    v2f m1p[3] = {{1.f, 1.f}, {as1, bs1}, {ac1, bc1}};
    v2f m2p[3] = {{1.f, 1.f}, {as2, bs2}, {ac2, bc2}};
    v2f m3p[3] = {{1.f, 1.f}, {as3, bs3}, {ac3, bc3}};
    v2f M01[9], M23[9];
#pragma unroll
    for (int a = 0; a < 3; ++a)
#pragma unroll
        for (int c = 0; c < 3; ++c) {
            M01[a * 3 + c] = m0p[a] * m1p[c];   // v_pk_mul_f32
            M23[a * 3 + c] = m2p[a] * m3p[c];
        }

    v2f e0 = {0.f, 0.f}, e1 = {0.f, 0.f}, e2 = {0.f, 0.f}, e3 = {0.f, 0.f};
#pragma unroll
    for (int t01 = 0; t01 < 9; ++t01) {
        v2f h0 = {0.f, 0.f}, h1 = {0.f, 0.f}, h2 = {0.f, 0.f}, h3 = {0.f, 0.f};
#pragma unroll
        for (int t23 = 0; t23 < 9; ++t23) {
            const float4 c4 = *(const float4*)&C[(t01 * 9 + t23) * 4];
            v2f mv = M23[t23];
            h0 = vfma(mv, c4.x, h0);            // v_pk_fma_f32
            h1 = vfma(mv, c4.y, h1);
            h2 = vfma(mv, c4.z, h2);
            h3 = vfma(mv, c4.w, h3);
        }
        v2f mu = M01[t01];
        e0 = __builtin_elementwise_fma(mu, h0, e0);
        e1 = __builtin_elementwise_fma(mu, h1, e1);
        e2 = __builtin_elementwise_fma(mu, h2, e2);
        e3 = __builtin_elementwise_fma(mu, h3, e3);
    }
    out[i]        = make_float4(e0.x, e1.x, e2.x, e3.x);
    out[i + half] = make_float4(e0.y, e1.y, e2.y, e3.y);
}

extern "C" void kernel_launch(void* const* d_in, const int* in_sizes, int n_in,
                              void* d_out, int out_size, void* d_ws, size_t ws_size,
                              hipStream_t stream) {
    const float4* x  = (const float4*)d_in[0];   // (B,4) float32
    const float*  qw = (const float*)d_in[1];    // (4,4,3) float32
    float* Cg = (float*)d_ws;                    // 324 floats
    float4* out = (float4*)d_out;                // (B,4) float32
    int B = in_sizes[0] / 4;

    hipLaunchKernelGGL(build_C, dim3(1), dim3(256), 0, stream, qw, Cg);

    int half = B >> 1;
    int blocks = (half + 255) / 256;
    if (blocks < 1) blocks = 1;
    hipLaunchKernelGGL(qlayer_main, dim3(blocks), dim3(256), 0, stream,
                       x, Cg, out, B);
}

// Round 11
// 79.788 us; speedup vs baseline: 1.0647x; 1.0647x over previous
//
#include <hip/hip_runtime.h>
#include <math.h>

// ---------------------------------------------------------------------------
// 4-qubit statevector layer, fully collapsed (FINAL, measured-best config):
//   e_w = sum_{t in {I,X,Z}^4} C_w[t] * prod_k m_k[t_k],  m_k = [1, sin x, cos x]
// Two kernels: build_C (1 block, writes C=4x81 to d_ws) + qlayer_main
// (2 samples/thread, C staged in LDS, wave-uniform broadcast reads).
// Reproduced 81.1 us (R4) / 80.9 us (R9). Total is dominated by the harness's
// fixed ~69us poison/restore chain (256MiB ws fill at 76% HBM peak); qlayer
// itself sits at its 32MB HBM floor (~5-8 us). pk_fma (R10), 4spt (R6/R8),
// scalar-pipe C (R7), and fused C-build (R5) all measured neutral-to-worse.
// ---------------------------------------------------------------------------

__global__ __launch_bounds__(256) void build_C(const float* __restrict__ qw,
                                               float* __restrict__ Cg) {
    __shared__ float g[16][8];          // per-gate 2x2 complex entries
    __shared__ float Ar[2][16][16];     // ping-pong Re state [buf][amp][col]
    __shared__ float Ai[2][16][16];
    __shared__ float ReE[4][16][16];    // Re(U^dag Z_w U)
    int t = threadIdx.x;
    int b = t >> 4, col = t & 15;

    if (t < 16) {
        float phi = qw[t * 3 + 0], theta = qw[t * 3 + 1], omega = qw[t * 3 + 2];
        float st, ct, sha, cha, shd, chd;
        __sincosf(0.5f * theta, &st, &ct);
        __sincosf(0.5f * (phi + omega), &sha, &cha);   // em = cha - i*sha
        __sincosf(0.5f * (phi - omega), &shd, &chd);   // ed = chd + i*shd
        g[t][0] =  cha * ct; g[t][1] = -sha * ct;   // u00
        g[t][2] = -chd * st; g[t][3] = -shd * st;   // u01
        g[t][4] =  chd * st; g[t][5] = -shd * st;   // u10
        g[t][6] =  cha * ct; g[t][7] =  sha * ct;   // u11
    }
    Ar[0][b][col] = (b == col) ? 1.f : 0.f;
    Ai[0][b][col] = 0.f;
    __syncthreads();

    // CNOT-ring permutation: new[b] = old[perm(b)]
    int perm = b;
#pragma unroll
    for (int w = 3; w >= 0; --w) {
        int cm = 8 >> w, tm = 8 >> ((w + 1) & 3);
        perm = (perm & cm) ? (perm ^ tm) : perm;
    }

    int p = 0;
    for (int l = 0; l < 4; ++l) {
#pragma unroll
        for (int w = 0; w < 4; ++w) {
            int gi = l * 4 + w;
            int m = 8 >> w;              // wire w <-> bit (3-w)
            int lo = b & ~m, hi = b | m;
            bool isHi = (b & m) != 0;
            float cAr = isHi ? g[gi][4] : g[gi][0];
            float cAi = isHi ? g[gi][5] : g[gi][1];
            float cBr = isHi ? g[gi][6] : g[gi][2];
            float cBi = isHi ? g[gi][7] : g[gi][3];
            float alor = Ar[p][lo][col], aloi = Ai[p][lo][col];
            float ahir = Ar[p][hi][col], ahii = Ai[p][hi][col];
            float nr = cAr * alor - cAi * aloi + cBr * ahir - cBi * ahii;
            float ni = cAr * aloi + cAi * alor + cBr * ahii + cBi * ahir;
            Ar[1 - p][b][col] = nr;
            Ai[1 - p][b][col] = ni;
            p = 1 - p;
            __syncthreads();
        }
        float nr = Ar[p][perm][col], ni = Ai[p][perm][col];
        Ar[1 - p][b][col] = nr;
        Ai[1 - p][b][col] = ni;
        p = 1 - p;
        __syncthreads();
    }

    // ReE_w[i][j] = sum_b z_w(b) * (Ur[b][i]Ur[b][j] + Ui[b][i]Ui[b][j])
    for (int idx = t; idx < 1024; idx += 256) {
        int w = idx >> 8, i = (idx >> 4) & 15, j = idx & 15;
        float acc = 0.f;
#pragma unroll
        for (int bb = 0; bb < 16; ++bb) {
            float z = ((bb >> (3 - w)) & 1) ? -1.f : 1.f;
            acc += z * (Ar[p][bb][i] * Ar[p][bb][j] + Ai[p][bb][i] * Ai[p][bb][j]);
        }
        ReE[w][i][j] = acc;
    }
    __syncthreads();

    // C[(t01*9+t23)*4 + w] = (1/16) sum_i sign_t(i) ReE_w[i][i^xmask]
    for (int idx = t; idx < 324; idx += 256) {
        int w = idx & 3, tt = idx >> 2;
        int t01 = tt / 9, t23 = tt % 9;
        int d0 = t01 / 3, d1 = t01 % 3, d2 = t23 / 3, d3 = t23 % 3;  // 0=I,1=X,2=Z
        int xmask = ((d0 == 1) << 3) | ((d1 == 1) << 2) | ((d2 == 1) << 1) | (d3 == 1);
        int zmask = ((d0 == 2) << 3) | ((d1 == 2) << 2) | ((d2 == 2) << 1) | (d3 == 2);
        float acc = 0.f;
#pragma unroll
        for (int i = 0; i < 16; ++i) {
            float sgn = (__popc(i & zmask) & 1) ? -1.f : 1.f;
            acc += sgn * ReE[w][i][i ^ xmask];
        }
        Cg[idx] = acc * 0.0625f;
    }
}

__global__ __launch_bounds__(256) void qlayer_main(
        const float4* __restrict__ x, const float* __restrict__ Cg,
        float4* __restrict__ out, int B) {
    __shared__ __align__(16) float C[324];
    for (int k = threadIdx.x; k < 324; k += 256) C[k] = Cg[k];
    __syncthreads();

    int half = B >> 1;
    int i = blockIdx.x * 256 + threadIdx.x;
    if (i >= half) {
        // odd-B tail (not hit for B=1M, kept for safety)
        if (i == half && (B & 1)) {
            float4 xv = x[B - 1];
            float s0, c0, s1, c1, s2, c2, s3, c3;
            __sincosf(xv.x, &s0, &c0); __sincosf(xv.y, &s1, &c1);
            __sincosf(xv.z, &s2, &c2); __sincosf(xv.w, &s3, &c3);
            float m0[3] = {1.f, s0, c0}, m1[3] = {1.f, s1, c1};
            float m2[3] = {1.f, s2, c2}, m3[3] = {1.f, s3, c3};
            float e0 = 0.f, e1 = 0.f, e2 = 0.f, e3 = 0.f;
            for (int t01 = 0; t01 < 9; ++t01)
                for (int t23 = 0; t23 < 9; ++t23) {
                    float mv = m0[t01 / 3] * m1[t01 % 3] * m2[t23 / 3] * m3[t23 % 3];
                    const float4 c4 = *(const float4*)&C[(t01 * 9 + t23) * 4];
                    e0 = fmaf(c4.x, mv, e0); e1 = fmaf(c4.y, mv, e1);
                    e2 = fmaf(c4.z, mv, e2); e3 = fmaf(c4.w, mv, e3);
                }
            out[B - 1] = make_float4(e0, e1, e2, e3);
        }
        return;
    }

    float4 xa = x[i];
    float4 xb = x[i + half];
    float as0, ac0, as1, ac1, as2, ac2, as3, ac3;
    float bs0, bc0, bs1, bc1, bs2, bc2, bs3, bc3;
    __sincosf(xa.x, &as0, &ac0); __sincosf(xa.y, &as1, &ac1);
    __sincosf(xa.z, &as2, &ac2); __sincosf(xa.w, &as3, &ac3);
    __sincosf(xb.x, &bs0, &bc0); __sincosf(xb.y, &bs1, &bc1);
    __sincosf(xb.z, &bs2, &bc2); __sincosf(xb.w, &bs3, &bc3);

    float am0[3] = {1.f, as0, ac0}, am1[3] = {1.f, as1, ac1};
    float am2[3] = {1.f, as2, ac2}, am3[3] = {1.f, as3, ac3};
    float bm0[3] = {1.f, bs0, bc0}, bm1[3] = {1.f, bs1, bc1};
    float bm2[3] = {1.f, bs2, bc2}, bm3[3] = {1.f, bs3, bc3};
    float aM01[9], aM23[9], bM01[9], bM23[9];
#pragma unroll
    for (int a = 0; a < 3; ++a)
#pragma unroll
        for (int c = 0; c < 3; ++c) {
            aM01[a * 3 + c] = am0[a] * am1[c];
            aM23[a * 3 + c] = am2[a] * am3[c];
            bM01[a * 3 + c] = bm0[a] * bm1[c];
            bM23[a * 3 + c] = bm2[a] * bm3[c];
        }

    float ae0 = 0.f, ae1 = 0.f, ae2 = 0.f, ae3 = 0.f;
    float be0 = 0.f, be1 = 0.f, be2 = 0.f, be3 = 0.f;
#pragma unroll
    for (int t01 = 0; t01 < 9; ++t01) {
        float ah0 = 0.f, ah1 = 0.f, ah2 = 0.f, ah3 = 0.f;
        float bh0 = 0.f, bh1 = 0.f, bh2 = 0.f, bh3 = 0.f;
#pragma unroll
        for (int t23 = 0; t23 < 9; ++t23) {
            const float4 c4 = *(const float4*)&C[(t01 * 9 + t23) * 4];
            float av = aM23[t23], bv = bM23[t23];
            ah0 = fmaf(c4.x, av, ah0); bh0 = fmaf(c4.x, bv, bh0);
            ah1 = fmaf(c4.y, av, ah1); bh1 = fmaf(c4.y, bv, bh1);
            ah2 = fmaf(c4.z, av, ah2); bh2 = fmaf(c4.z, bv, bh2);
            ah3 = fmaf(c4.w, av, ah3); bh3 = fmaf(c4.w, bv, bh3);
        }
        float au = aM01[t01], bu = bM01[t01];
        ae0 = fmaf(au, ah0, ae0); be0 = fmaf(bu, bh0, be0);
        ae1 = fmaf(au, ah1, ae1); be1 = fmaf(bu, bh1, be1);
        ae2 = fmaf(au, ah2, ae2); be2 = fmaf(bu, bh2, be2);
        ae3 = fmaf(au, ah3, ae3); be3 = fmaf(bu, bh3, be3);
    }
    out[i]        = make_float4(ae0, ae1, ae2, ae3);
    out[i + half] = make_float4(be0, be1, be2, be3);
}

extern "C" void kernel_launch(void* const* d_in, const int* in_sizes, int n_in,
                              void* d_out, int out_size, void* d_ws, size_t ws_size,
                              hipStream_t stream) {
    const float4* x  = (const float4*)d_in[0];   // (B,4) float32
    const float*  qw = (const float*)d_in[1];    // (4,4,3) float32
    float* Cg = (float*)d_ws;                    // 324 floats
    float4* out = (float4*)d_out;                // (B,4) float32
    int B = in_sizes[0] / 4;

    hipLaunchKernelGGL(build_C, dim3(1), dim3(256), 0, stream, qw, Cg);

    int half = B >> 1;
    int blocks = (half + 255) / 256;
    if (blocks < 1) blocks = 1;
    hipLaunchKernelGGL(qlayer_main, dim3(blocks), dim3(256), 0, stream,
                       x, Cg, out, B);
}